// Round 1
// baseline (1810.676 us; speedup 1.0000x reference)
//
#include <hip/hip_runtime.h>
#include <hip/hip_bf16.h>

#define BATCH 8
#define HH 128
#define WW 128
#define CC 256
#define OCC 512

typedef __bf16 bf16x8 __attribute__((ext_vector_type(8)));
typedef float f32x4 __attribute__((ext_vector_type(4)));

// Transpose+convert weights: K[ky][kx][ic][oc] (f32) -> Wt[tap][oc][ic] (bf16)
// total elements 9*256*512 = 1,179,648 = 4608 * 256
__global__ void prep_weights(const float* __restrict__ k, __bf16* __restrict__ wt) {
    int idx = blockIdx.x * 256 + threadIdx.x;
    int oc   = idx & 511;
    int rest = idx >> 9;
    int ic   = rest & 255;
    int tap  = rest >> 8;
    wt[(tap * OCC + oc) * CC + ic] = (__bf16)k[idx];
}

// Fused: conv row `cr` x oc-tile (128 wide) as a 128x128x2304 bf16 MFMA GEMM,
// then in-lane unscramble + bilinear sample, writing final output directly.
__global__ __launch_bounds__(256, 2)
void conv_offset_sample(const float* __restrict__ x, const __bf16* __restrict__ wt,
                        const float* __restrict__ bias, float* __restrict__ out) {
    const int bi  = blockIdx.x;
    const int ncb = bi & 3;          // oc chunk 0..3
    const int cr  = (bi >> 2) & 127; // conv row 0..127
    const int b   = bi >> 9;         // batch 0..7
    const int oc0 = ncb * 128;

    const int tid  = threadIdx.x;
    const int lane = tid & 63;
    const int wid  = tid >> 6;   // 4 waves
    const int wm   = wid >> 1;   // 0..1 (M half)
    const int wn   = wid & 1;    // 0..1 (N half)
    const int l15  = lane & 15;
    const int lg   = lane >> 4;

    const float* xb = x + (size_t)b * (HH * WW * CC);

    f32x4 acc[4][4] = {};

#pragma unroll 1
    for (int tap = 0; tap < 9; ++tap) {
        const int dy = tap / 3 - 1;
        const int dx = tap - (tap / 3) * 3 - 1;
        const int row = cr + dy;
        const bool rowok = (unsigned)row < (unsigned)HH;
        const float* xrow = xb + row * (WW * CC);
        const __bf16* wtap = wt + (size_t)tap * (OCC * CC);

        for (int icc = 0; icc < CC; icc += 32) {
            const int ic = icc + lg * 8;

            bf16x8 afrag[4];
#pragma unroll
            for (int mi = 0; mi < 4; ++mi) {
                const int col = wm * 64 + mi * 16 + l15 + dx;
                f32x4 v0 = {0.f, 0.f, 0.f, 0.f};
                f32x4 v1 = {0.f, 0.f, 0.f, 0.f};
                if (rowok && (unsigned)col < (unsigned)WW) {
                    const f32x4* p = (const f32x4*)(xrow + col * CC + ic);
                    v0 = p[0];
                    v1 = p[1];
                }
                bf16x8 a;
                a[0] = (__bf16)v0[0]; a[1] = (__bf16)v0[1];
                a[2] = (__bf16)v0[2]; a[3] = (__bf16)v0[3];
                a[4] = (__bf16)v1[0]; a[5] = (__bf16)v1[1];
                a[6] = (__bf16)v1[2]; a[7] = (__bf16)v1[3];
                afrag[mi] = a;
            }

            bf16x8 bfrag[4];
#pragma unroll
            for (int ni = 0; ni < 4; ++ni) {
                const int oc = oc0 + wn * 64 + ni * 16 + l15;
                bfrag[ni] = *(const bf16x8*)(wtap + oc * CC + ic);
            }

#pragma unroll
            for (int mi = 0; mi < 4; ++mi)
#pragma unroll
                for (int ni = 0; ni < 4; ++ni)
                    acc[mi][ni] = __builtin_amdgcn_mfma_f32_16x16x32_bf16(
                        afrag[mi], bfrag[ni], acc[mi][ni], 0, 0, 0);
        }
    }

    // ---- Epilogue: unscramble + bilinear sampling (all in-lane) ----
    // conv(b, cr, j, oc) is offset component k=j&1 for output
    //   (b, i2 = (cr>>1) + 64*(oc&1), j2 = (cr&1)*64 + (j>>1), p = oc>>1)
    const int ibase = cr >> 1;
    const int jbase = (cr & 1) * 64;

#pragma unroll
    for (int ni = 0; ni < 4; ++ni) {
        const int oc = oc0 + wn * 64 + ni * 16 + l15;
        const float bv = bias[oc];
        const int p  = oc >> 1;
        const int i2 = ibase + ((oc & 1) << 6);
        const float* xp = x + (size_t)b * (HH * WW * CC) + p;
        float* op = out + (((size_t)b * HH + i2) * WW) * CC + p;

#pragma unroll
        for (int mi = 0; mi < 4; ++mi) {
#pragma unroll
            for (int s = 0; s < 2; ++s) {
                // acc row = lg*4 + (2s+k); pixel j = wm*64 + mi*16 + lg*4 + 2s + k
                const int u  = wm * 32 + mi * 8 + lg * 2 + s; // = j>>1
                const int j2 = jbase + u;

                float c0 = acc[mi][ni][2 * s]     + bv + (float)i2; // row coord
                float c1 = acc[mi][ni][2 * s + 1] + bv + (float)j2; // col coord
                c0 = fminf(fmaxf(c0, 0.f), 127.f);
                c1 = fminf(fmaxf(c1, 0.f), 127.f);

                const int lt0 = (int)floorf(c0);
                const int rb0 = (int)ceilf(c0);
                const int lt1 = (int)floorf(c1);
                const int rb1 = (int)ceilf(c1);
                const float f0 = c0 - (float)lt0;
                const float f1 = c1 - (float)lt1;

                const float vlt = xp[(lt0 * WW + lt1) * CC];
                const float vrb = xp[(rb0 * WW + rb1) * CC];
                const float vlb = xp[(lt0 * WW + rb1) * CC];
                const float vrt = xp[(rb0 * WW + lt1) * CC];

                const float vt = vlt + (vrt - vlt) * f0;
                const float vb = vlb + (vrb - vlb) * f0;
                op[(size_t)j2 * CC] = vt + (vb - vt) * f1;
            }
        }
    }
}

extern "C" void kernel_launch(void* const* d_in, const int* in_sizes, int n_in,
                              void* d_out, int out_size, void* d_ws, size_t ws_size,
                              hipStream_t stream) {
    const float* x    = (const float*)d_in[0];
    const float* kern = (const float*)d_in[1];
    const float* bias = (const float*)d_in[2];
    float* out = (float*)d_out;
    __bf16* wt = (__bf16*)d_ws;  // 9*512*256*2 = 2,359,296 bytes

    prep_weights<<<4608, 256, 0, stream>>>(kern, wt);
    conv_offset_sample<<<4096, 256, 0, stream>>>(x, wt, bias, out);
}